// Round 6
// baseline (3147.942 us; speedup 1.0000x reference)
//
#include <hip/hip_runtime.h>
#include <hip/hip_bf16.h>
#include <stdint.h>

#define Bn   16
#define Nn   4096
#define Sn   1024
#define Kn   8
#define CINn 128
#define COUTn 256

// Exact f32 squared distance, no FMA contraction: matches ((dx*dx+dy*dy)+dz*dz)
static __device__ __forceinline__ float sqdist(float ax, float ay, float az,
                                               float bx, float by, float bz) {
    float dx = __fsub_rn(ax, bx);
    float dy = __fsub_rn(ay, by);
    float dz = __fsub_rn(az, bz);
    return __fadd_rn(__fadd_rn(__fmul_rn(dx, dx), __fmul_rn(dy, dy)), __fmul_rn(dz, dz));
}

// ---------------- Kernel: farthest point sampling (VALIDATED by output 0) ---
__global__ __launch_bounds__(512) void k_fps(const float* __restrict__ xyz,
                                             float* __restrict__ out_xyz) {
    __shared__ __align__(16) float xs[Nn], ys[Nn], zs[Nn];
    __shared__ unsigned long long sred[8];
    __shared__ int slast;
    const int b = blockIdx.x;
    const int tid = threadIdx.x;
    const float* base = xyz + (size_t)b * 3 * Nn;
    for (int i = tid; i < Nn; i += 512) {
        xs[i] = base[i];
        ys[i] = base[Nn + i];
        zs[i] = base[2 * Nn + i];
    }
    __syncthreads();
    float px[8], py[8], pz[8], dist[8];
#pragma unroll
    for (int j = 0; j < 8; ++j) {
        int p = tid + j * 512;
        px[j] = xs[p]; py[j] = ys[p]; pz[j] = zs[p];
        dist[j] = 3.402823466e+38f;   // FLT_MAX, matches jnp.finfo(f32).max
    }
    int last = 0;
    if (tid == 0) {
        out_xyz[(size_t)(b * Sn) * 3 + 0] = xs[0];
        out_xyz[(size_t)(b * Sn) * 3 + 1] = ys[0];
        out_xyz[(size_t)(b * Sn) * 3 + 2] = zs[0];
    }
    for (int s = 1; s < Sn; ++s) {
        float cx = xs[last], cy = ys[last], cz = zs[last];
        float mv = -1.0f; int mi = 0;
#pragma unroll
        for (int j = 0; j < 8; ++j) {
            float d = sqdist(px[j], py[j], pz[j], cx, cy, cz);
            float nd = fminf(dist[j], d);
            dist[j] = nd;
            if (nd > mv) { mv = nd; mi = tid + j * 512; }  // strict >: first-max wins
        }
        unsigned long long key =
            ((unsigned long long)__float_as_uint(mv) << 32) | (unsigned)(Nn - 1 - mi);
#pragma unroll
        for (int off = 32; off >= 1; off >>= 1) {
            unsigned long long other = __shfl_xor(key, off);
            if (other > key) key = other;
        }
        if ((tid & 63) == 0) sred[tid >> 6] = key;
        __syncthreads();
        if (tid < 64) {
            unsigned long long k2 = sred[tid & 7];
#pragma unroll
            for (int off = 1; off < 8; off <<= 1) {
                unsigned long long other = __shfl_xor(k2, off);
                if (other > k2) k2 = other;
            }
            if (tid == 0) {
                int nl = Nn - 1 - (int)(unsigned)(k2 & 0xFFFFFFFFull);
                slast = nl;
                out_xyz[(size_t)(b * Sn + s) * 3 + 0] = xs[nl];
                out_xyz[(size_t)(b * Sn + s) * 3 + 1] = ys[nl];
                out_xyz[(size_t)(b * Sn + s) * 3 + 2] = zs[nl];
            }
        }
        __syncthreads();
        last = slast;
    }
}

// ---- NAIVE ball query: one thread per center, pure global loads, no LDS ----
__global__ __launch_bounds__(256) void k_ball(const float* __restrict__ xyz,
                                              const float* __restrict__ out_xyz,
                                              int* __restrict__ ball_idx) {
    const int c_glob = blockIdx.x * 256 + threadIdx.x;   // 0 .. B*S-1
    if (c_glob >= Bn * Sn) return;
    const int b = c_glob / Sn;
    const int c = c_glob % Sn;
    const float* base = xyz + (size_t)b * 3 * Nn;
    const float cx = out_xyz[(size_t)c_glob * 3 + 0];
    const float cy = out_xyz[(size_t)c_glob * 3 + 1];
    const float cz = out_xyz[(size_t)c_glob * 3 + 2];
    int found[Kn];
    int cnt = 0;
    for (int p = 0; p < Nn && cnt < Kn; ++p) {
        float d2 = sqdist(base[p], base[Nn + p], base[2 * Nn + p], cx, cy, cz);
        if (d2 <= 0.04f) found[cnt++] = p;   // f32(0.2*0.2); center itself has d2==0
    }
    for (int k2 = cnt; k2 < Kn; ++k2) found[k2] = found[0];
    for (int k2 = 0; k2 < Kn; ++k2)
        ball_idx[(size_t)c_glob * Kn + k2] = found[k2];
}

// ---- NAIVE feature kernel: one thread per (b,s,o). No LDS, no cooperation. -
// Literal reference order: for each k: dot over f, +bias, BN, ReLU; then max.
__global__ __launch_bounds__(256) void k_feat(const float* __restrict__ feat,
                                              const float* __restrict__ conv_w,
                                              const float* __restrict__ conv_b,
                                              const float* __restrict__ bn_g,
                                              const float* __restrict__ bn_b,
                                              const float* __restrict__ bn_m,
                                              const float* __restrict__ bn_v,
                                              const int* __restrict__ ball_idx,
                                              float* __restrict__ out_feat) {
    const int bs = blockIdx.x;           // 0 .. B*S-1
    const int o  = threadIdx.x;          // 0 .. 255
    const int b  = bs / Sn;
    const float* fb = feat + (size_t)b * CINn * Nn;
    const float* wo = conv_w + (size_t)o * CINn;
    const float bias = conv_b[o];
    const float g = bn_g[o], be = bn_b[o], mn = bn_m[o], vr = bn_v[o];
    const float inv = sqrtf(vr + 1e-5f);
    float mx = -3.402823466e+38f;
    for (int k = 0; k < Kn; ++k) {
        const int pt = ball_idx[(size_t)bs * Kn + k];
        float acc = 0.0f;
        for (int f = 0; f < CINn; ++f)
            acc += fb[(size_t)f * Nn + pt] * wo[f];
        float z = acc + bias;
        float y = g * (z - mn) / inv + be;
        y = fmaxf(y, 0.0f);              // ReLU before max, literal order
        mx = fmaxf(mx, y);
    }
    out_feat[(size_t)bs * COUTn + o] = mx;
}

extern "C" void kernel_launch(void* const* d_in, const int* in_sizes, int n_in,
                              void* d_out, int out_size, void* d_ws, size_t ws_size,
                              hipStream_t stream) {
    const float* xyz    = (const float*)d_in[0];
    const float* feat   = (const float*)d_in[1];
    const float* conv_w = (const float*)d_in[2];
    const float* conv_b = (const float*)d_in[3];
    const float* bn_g   = (const float*)d_in[4];
    const float* bn_b   = (const float*)d_in[5];
    const float* bn_m   = (const float*)d_in[6];
    const float* bn_v   = (const float*)d_in[7];

    float* out_xyz  = (float*)d_out;
    float* out_feat = out_xyz + (size_t)Bn * Sn * 3;

    int* ball_idx = (int*)d_ws;   // 512 KB

    k_fps <<<dim3(Bn),            dim3(512), 0, stream>>>(xyz, out_xyz);
    k_ball<<<dim3(Bn * Sn / 256), dim3(256), 0, stream>>>(xyz, out_xyz, ball_idx);
    k_feat<<<dim3(Bn * Sn),       dim3(256), 0, stream>>>(feat, conv_w, conv_b,
                                                          bn_g, bn_b, bn_m, bn_v,
                                                          ball_idx, out_feat);
}

// Round 8
// 1991.458 us; speedup vs baseline: 1.5807x; 1.5807x over previous
//
#include <hip/hip_runtime.h>
#include <hip/hip_bf16.h>
#include <stdint.h>

#define Bn   16
#define Nn   4096
#define Sn   1024
#define Kn   8
#define CINn 128
#define COUTn 256

// Exact f32 squared distance, no FMA contraction: matches ((dx*dx+dy*dy)+dz*dz)
static __device__ __forceinline__ float sqdist(float ax, float ay, float az,
                                               float bx, float by, float bz) {
    float dx = __fsub_rn(ax, bx);
    float dy = __fsub_rn(ay, by);
    float dz = __fsub_rn(az, bz);
    return __fadd_rn(__fadd_rn(__fmul_rn(dx, dx), __fmul_rn(dy, dy)), __fmul_rn(dz, dz));
}

// ---------------- Kernel: farthest point sampling (VALIDATED by output 0) ---
__global__ __launch_bounds__(512) void k_fps(const float* __restrict__ xyz,
                                             float* __restrict__ out_xyz) {
    __shared__ __align__(16) float xs[Nn], ys[Nn], zs[Nn];
    __shared__ unsigned long long sred[8];
    __shared__ int slast;
    const int b = blockIdx.x;
    const int tid = threadIdx.x;
    const float* base = xyz + (size_t)b * 3 * Nn;
    for (int i = tid; i < Nn; i += 512) {
        xs[i] = base[i];
        ys[i] = base[Nn + i];
        zs[i] = base[2 * Nn + i];
    }
    __syncthreads();
    float px[8], py[8], pz[8], dist[8];
#pragma unroll
    for (int j = 0; j < 8; ++j) {
        int p = tid + j * 512;
        px[j] = xs[p]; py[j] = ys[p]; pz[j] = zs[p];
        dist[j] = 3.402823466e+38f;   // FLT_MAX, matches jnp.finfo(f32).max
    }
    int last = 0;
    if (tid == 0) {
        out_xyz[(size_t)(b * Sn) * 3 + 0] = xs[0];
        out_xyz[(size_t)(b * Sn) * 3 + 1] = ys[0];
        out_xyz[(size_t)(b * Sn) * 3 + 2] = zs[0];
    }
    for (int s = 1; s < Sn; ++s) {
        float cx = xs[last], cy = ys[last], cz = zs[last];
        float mv = -1.0f; int mi = 0;
#pragma unroll
        for (int j = 0; j < 8; ++j) {
            float d = sqdist(px[j], py[j], pz[j], cx, cy, cz);
            float nd = fminf(dist[j], d);
            dist[j] = nd;
            if (nd > mv) { mv = nd; mi = tid + j * 512; }  // strict >: first-max wins
        }
        unsigned long long key =
            ((unsigned long long)__float_as_uint(mv) << 32) | (unsigned)(Nn - 1 - mi);
#pragma unroll
        for (int off = 32; off >= 1; off >>= 1) {
            unsigned long long other = __shfl_xor(key, off);
            if (other > key) key = other;
        }
        if ((tid & 63) == 0) sred[tid >> 6] = key;
        __syncthreads();
        if (tid < 64) {
            unsigned long long k2 = sred[tid & 7];
#pragma unroll
            for (int off = 1; off < 8; off <<= 1) {
                unsigned long long other = __shfl_xor(k2, off);
                if (other > k2) k2 = other;
            }
            if (tid == 0) {
                int nl = Nn - 1 - (int)(unsigned)(k2 & 0xFFFFFFFFull);
                slast = nl;
                out_xyz[(size_t)(b * Sn + s) * 3 + 0] = xs[nl];
                out_xyz[(size_t)(b * Sn + s) * 3 + 1] = ys[nl];
                out_xyz[(size_t)(b * Sn + s) * 3 + 2] = zs[nl];
            }
        }
        __syncthreads();
        last = slast;
    }
}

// ---- Ball query: VALIDATED r6 version — one thread per center, global loads.
__global__ __launch_bounds__(256) void k_ball(const float* __restrict__ xyz,
                                              const float* __restrict__ out_xyz,
                                              int* __restrict__ ball_idx) {
    const int c_glob = blockIdx.x * 256 + threadIdx.x;   // 0 .. B*S-1
    if (c_glob >= Bn * Sn) return;
    const int b = c_glob / Sn;
    const float* base = xyz + (size_t)b * 3 * Nn;
    const float cx = out_xyz[(size_t)c_glob * 3 + 0];
    const float cy = out_xyz[(size_t)c_glob * 3 + 1];
    const float cz = out_xyz[(size_t)c_glob * 3 + 2];
    int found[Kn];
    int cnt = 0;
    for (int p = 0; p < Nn && cnt < Kn; ++p) {
        float d2 = sqdist(base[p], base[Nn + p], base[2 * Nn + p], cx, cy, cz);
        if (d2 <= 0.04f) found[cnt++] = p;   // f32(0.2*0.2); center itself has d2==0
    }
    for (int k2 = cnt; k2 < Kn; ++k2) found[k2] = found[0];
    for (int k2 = 0; k2 < Kn; ++k2)
        ball_idx[(size_t)c_glob * Kn + k2] = found[k2];
}

// ---- Feature kernel: SAME structure as validated r6 (1 thread per (bs,o),
// no LDS, no syncs) — only the loop order changed: f outer with float4 W
// loads held in registers, k inner over 8 independent accumulators.
__global__ __launch_bounds__(256) void k_feat(const float* __restrict__ feat,
                                              const float* __restrict__ conv_w,
                                              const float* __restrict__ conv_b,
                                              const float* __restrict__ bn_g,
                                              const float* __restrict__ bn_b,
                                              const float* __restrict__ bn_m,
                                              const float* __restrict__ bn_v,
                                              const int* __restrict__ ball_idx,
                                              float* __restrict__ out_feat) {
    const int bs = blockIdx.x;           // 0 .. B*S-1
    const int o  = threadIdx.x;          // 0 .. 255
    const int b  = bs / Sn;
    const float* fb = feat + (size_t)b * CINn * Nn;
    const float* wo = conv_w + (size_t)o * CINn;

    int pt[Kn];
#pragma unroll
    for (int k = 0; k < Kn; ++k) pt[k] = ball_idx[(size_t)bs * Kn + k];

    float acc[Kn];
#pragma unroll
    for (int k = 0; k < Kn; ++k) acc[k] = 0.0f;

    for (int f4 = 0; f4 < CINn / 4; ++f4) {
        const float4 w4 = *(const float4*)&wo[f4 * 4];
        const float* fr0 = fb + (size_t)(f4 * 4 + 0) * Nn;
        const float* fr1 = fb + (size_t)(f4 * 4 + 1) * Nn;
        const float* fr2 = fb + (size_t)(f4 * 4 + 2) * Nn;
        const float* fr3 = fb + (size_t)(f4 * 4 + 3) * Nn;
#pragma unroll
        for (int k = 0; k < Kn; ++k) {
            acc[k] += fr0[pt[k]] * w4.x;
            acc[k] += fr1[pt[k]] * w4.y;
            acc[k] += fr2[pt[k]] * w4.z;
            acc[k] += fr3[pt[k]] * w4.w;
        }
    }

    // epilogue: byte-identical math to validated r6 kernel
    const float bias = conv_b[o];
    const float g = bn_g[o], be = bn_b[o], mn = bn_m[o], vr = bn_v[o];
    const float inv = sqrtf(vr + 1e-5f);
    float mx = -3.402823466e+38f;
#pragma unroll
    for (int k = 0; k < Kn; ++k) {
        float z = acc[k] + bias;
        float y = g * (z - mn) / inv + be;
        y = fmaxf(y, 0.0f);              // ReLU before max, literal order
        mx = fmaxf(mx, y);
    }
    out_feat[(size_t)bs * COUTn + o] = mx;
}

extern "C" void kernel_launch(void* const* d_in, const int* in_sizes, int n_in,
                              void* d_out, int out_size, void* d_ws, size_t ws_size,
                              hipStream_t stream) {
    const float* xyz    = (const float*)d_in[0];
    const float* feat   = (const float*)d_in[1];
    const float* conv_w = (const float*)d_in[2];
    const float* conv_b = (const float*)d_in[3];
    const float* bn_g   = (const float*)d_in[4];
    const float* bn_b   = (const float*)d_in[5];
    const float* bn_m   = (const float*)d_in[6];
    const float* bn_v   = (const float*)d_in[7];

    float* out_xyz  = (float*)d_out;
    float* out_feat = out_xyz + (size_t)Bn * Sn * 3;

    int* ball_idx = (int*)d_ws;   // 512 KB

    k_fps <<<dim3(Bn),            dim3(512), 0, stream>>>(xyz, out_xyz);
    k_ball<<<dim3(Bn * Sn / 256), dim3(256), 0, stream>>>(xyz, out_xyz, ball_idx);
    k_feat<<<dim3(Bn * Sn),       dim3(256), 0, stream>>>(feat, conv_w, conv_b,
                                                          bn_g, bn_b, bn_m, bn_v,
                                                          ball_idx, out_feat);
}

// Round 9
// 1709.684 us; speedup vs baseline: 1.8412x; 1.1648x over previous
//
#include <hip/hip_runtime.h>
#include <hip/hip_bf16.h>
#include <stdint.h>

#define Bn   16
#define Nn   4096
#define Sn   1024
#define Kn   8
#define CINn 128
#define COUTn 256

// Exact f32 squared distance, no FMA contraction: matches ((dx*dx+dy*dy)+dz*dz)
static __device__ __forceinline__ float sqdist(float ax, float ay, float az,
                                               float bx, float by, float bz) {
    float dx = __fsub_rn(ax, bx);
    float dy = __fsub_rn(ay, by);
    float dz = __fsub_rn(az, bz);
    return __fadd_rn(__fadd_rn(__fmul_rn(dx, dx), __fmul_rn(dy, dy)), __fmul_rn(dz, dz));
}

static __device__ __forceinline__ unsigned long long u64max(unsigned long long a,
                                                            unsigned long long b) {
    return a > b ? a : b;
}

// ---------------- Kernel: farthest point sampling ---------------------------
// Same exact argmax/tie-break semantics as the validated version; reduction
// restructured: double-buffered key array + ONE barrier per step, every wave
// redundantly reduces all 512 keys (8 strided b64 reads + tree + 6 shfl).
__global__ __launch_bounds__(512) void k_fps(const float* __restrict__ xyz,
                                             float* __restrict__ out_xyz) {
    __shared__ __align__(16) float xs[Nn], ys[Nn], zs[Nn];
    __shared__ unsigned long long kbuf[2][512];
    const int b = blockIdx.x;
    const int tid = threadIdx.x;
    const int lane = tid & 63;
    const float* base = xyz + (size_t)b * 3 * Nn;
    for (int i = tid; i < Nn; i += 512) {
        xs[i] = base[i];
        ys[i] = base[Nn + i];
        zs[i] = base[2 * Nn + i];
    }
    __syncthreads();
    float px[8], py[8], pz[8], dist[8];
#pragma unroll
    for (int j = 0; j < 8; ++j) {
        int p = tid + j * 512;
        px[j] = xs[p]; py[j] = ys[p]; pz[j] = zs[p];
        dist[j] = 3.402823466e+38f;   // FLT_MAX, matches jnp.finfo(f32).max
    }
    int last = 0;
    if (tid == 0) {
        out_xyz[(size_t)(b * Sn) * 3 + 0] = xs[0];
        out_xyz[(size_t)(b * Sn) * 3 + 1] = ys[0];
        out_xyz[(size_t)(b * Sn) * 3 + 2] = zs[0];
    }
    for (int s = 1; s < Sn; ++s) {
        const float cx = xs[last], cy = ys[last], cz = zs[last];
        float mv = -1.0f; int mi = 0;
#pragma unroll
        for (int j = 0; j < 8; ++j) {
            float d = sqdist(px[j], py[j], pz[j], cx, cy, cz);
            float nd = fminf(dist[j], d);
            dist[j] = nd;
            if (nd > mv) { mv = nd; mi = tid + j * 512; }  // strict >: first-max wins
        }
        // pack: dist bits high (dist>=0 so f32 bit order == value order),
        // (N-1-idx) low so u64-max tie-breaks to the SMALLEST index.
        kbuf[s & 1][tid] =
            ((unsigned long long)__float_as_uint(mv) << 32) | (unsigned)(Nn - 1 - mi);
        __syncthreads();
        // stage 1: each lane reads 8 strided keys (identical work in all waves)
        unsigned long long r0 = kbuf[s & 1][lane];
        unsigned long long r1 = kbuf[s & 1][lane + 64];
        unsigned long long r2 = kbuf[s & 1][lane + 128];
        unsigned long long r3 = kbuf[s & 1][lane + 192];
        unsigned long long r4 = kbuf[s & 1][lane + 256];
        unsigned long long r5 = kbuf[s & 1][lane + 320];
        unsigned long long r6 = kbuf[s & 1][lane + 384];
        unsigned long long r7 = kbuf[s & 1][lane + 448];
        unsigned long long key = u64max(u64max(u64max(r0, r1), u64max(r2, r3)),
                                        u64max(u64max(r4, r5), u64max(r6, r7)));
        // stage 2: 6-level butterfly across the wave
#pragma unroll
        for (int off = 32; off >= 1; off >>= 1) {
            unsigned long long other = __shfl_xor(key, off);
            if (other > key) key = other;
        }
        const int nl = Nn - 1 - (int)(unsigned)(key & 0xFFFFFFFFull);
        if (tid == 0) {
            out_xyz[(size_t)(b * Sn + s) * 3 + 0] = xs[nl];
            out_xyz[(size_t)(b * Sn + s) * 3 + 1] = ys[nl];
            out_xyz[(size_t)(b * Sn + s) * 3 + 2] = zs[nl];
        }
        last = nl;
        // no second barrier: next step writes the OTHER kbuf half; writes to
        // this half recur only after the s+1 barrier, which each wave reaches
        // only after completing this step's reads (program order).
    }
}

// ---- Ball query: validated serial-scan semantics, xyz staged in LDS --------
__global__ __launch_bounds__(256) void k_ball(const float* __restrict__ xyz,
                                              const float* __restrict__ out_xyz,
                                              int* __restrict__ ball_idx) {
    __shared__ __align__(16) float xs[Nn], ys[Nn], zs[Nn];
    const int b = blockIdx.x >> 2;          // 4 blocks per batch
    const int c = (blockIdx.x & 3) * 256 + threadIdx.x;
    const int tid = threadIdx.x;
    const float* base = xyz + (size_t)b * 3 * Nn;
    for (int i = tid; i < Nn; i += 256) {
        xs[i] = base[i]; ys[i] = base[Nn + i]; zs[i] = base[2 * Nn + i];
    }
    __syncthreads();
    const float cx = out_xyz[(size_t)(b * Sn + c) * 3 + 0];
    const float cy = out_xyz[(size_t)(b * Sn + c) * 3 + 1];
    const float cz = out_xyz[(size_t)(b * Sn + c) * 3 + 2];
    int found[Kn];
    int cnt = 0;
    for (int p = 0; p < Nn && cnt < Kn; ++p) {
        float d2 = sqdist(xs[p], ys[p], zs[p], cx, cy, cz);
        if (d2 <= 0.04f) found[cnt++] = p;   // f32(0.2*0.2); center itself has d2==0
    }
    for (int k2 = cnt; k2 < Kn; ++k2) found[k2] = found[0];
    for (int k2 = 0; k2 < Kn; ++k2)
        ball_idx[(size_t)(b * Sn + c) * Kn + k2] = found[k2];
}

// ---- Feature kernel: one WAVE per center, each lane owns 4 out-channels ----
// No LDS, no syncs, no cross-thread cooperation (same safety class as the
// validated r6/r8 kernels). Per f4-chunk: 4 w-float4 + 32 broadcast feat
// loads feed 128 FMAs (8 k x 4 o x 4 f).
__global__ __launch_bounds__(256) void k_feat(const float* __restrict__ feat,
                                              const float* __restrict__ conv_w,
                                              const float* __restrict__ conv_b,
                                              const float* __restrict__ bn_g,
                                              const float* __restrict__ bn_b,
                                              const float* __restrict__ bn_m,
                                              const float* __restrict__ bn_v,
                                              const int* __restrict__ ball_idx,
                                              float* __restrict__ out_feat) {
    const int wave = threadIdx.x >> 6, lane = threadIdx.x & 63;
    const int bs = blockIdx.x * 4 + wave;     // 0 .. B*S-1
    const int b  = bs >> 10;                  // Sn = 1024
    const float* fb = feat + (size_t)b * CINn * Nn;
    const float4* cw4 = (const float4*)conv_w;   // [o][f/4]

    int pt[Kn];
#pragma unroll
    for (int k = 0; k < Kn; ++k) pt[k] = ball_idx[(size_t)bs * Kn + k];

    float acc[4][Kn];
#pragma unroll
    for (int j = 0; j < 4; ++j)
#pragma unroll
        for (int k = 0; k < Kn; ++k) acc[j][k] = 0.0f;

    for (int f4 = 0; f4 < CINn / 4; ++f4) {
        float4 w[4];
#pragma unroll
        for (int j = 0; j < 4; ++j)
            w[j] = cw4[(size_t)(lane + 64 * j) * (CINn / 4) + f4];
#pragma unroll
        for (int c = 0; c < 4; ++c) {
            const float* frc = fb + (size_t)(f4 * 4 + c) * Nn;
            float fv[Kn];
#pragma unroll
            for (int k = 0; k < Kn; ++k) fv[k] = frc[pt[k]];
#pragma unroll
            for (int j = 0; j < 4; ++j) {
                const float wc = ((const float*)&w[j])[c];
#pragma unroll
                for (int k = 0; k < Kn; ++k) acc[j][k] += fv[k] * wc;
            }
        }
    }

    // epilogue: identical math/order to the validated kernel
#pragma unroll
    for (int j = 0; j < 4; ++j) {
        const int o = lane + 64 * j;
        const float bias = conv_b[o];
        const float g = bn_g[o], be = bn_b[o], mn = bn_m[o], vr = bn_v[o];
        const float inv = sqrtf(vr + 1e-5f);
        float mx = -3.402823466e+38f;
#pragma unroll
        for (int k = 0; k < Kn; ++k) {
            float z = acc[j][k] + bias;
            float y = g * (z - mn) / inv + be;
            y = fmaxf(y, 0.0f);              // ReLU before max, literal order
            mx = fmaxf(mx, y);
        }
        out_feat[(size_t)bs * COUTn + o] = mx;
    }
}

extern "C" void kernel_launch(void* const* d_in, const int* in_sizes, int n_in,
                              void* d_out, int out_size, void* d_ws, size_t ws_size,
                              hipStream_t stream) {
    const float* xyz    = (const float*)d_in[0];
    const float* feat   = (const float*)d_in[1];
    const float* conv_w = (const float*)d_in[2];
    const float* conv_b = (const float*)d_in[3];
    const float* bn_g   = (const float*)d_in[4];
    const float* bn_b   = (const float*)d_in[5];
    const float* bn_m   = (const float*)d_in[6];
    const float* bn_v   = (const float*)d_in[7];

    float* out_xyz  = (float*)d_out;
    float* out_feat = out_xyz + (size_t)Bn * Sn * 3;

    int* ball_idx = (int*)d_ws;   // 512 KB

    k_fps <<<dim3(Bn),            dim3(512), 0, stream>>>(xyz, out_xyz);
    k_ball<<<dim3(Bn * 4),        dim3(256), 0, stream>>>(xyz, out_xyz, ball_idx);
    k_feat<<<dim3(Bn * Sn / 4),   dim3(256), 0, stream>>>(feat, conv_w, conv_b,
                                                          bn_g, bn_b, bn_m, bn_v,
                                                          ball_idx, out_feat);
}

// Round 10
// 1288.609 us; speedup vs baseline: 2.4429x; 1.3268x over previous
//
#include <hip/hip_runtime.h>
#include <hip/hip_bf16.h>
#include <stdint.h>

#define Bn   16
#define Nn   4096
#define Sn   1024
#define Kn   8
#define CINn 128
#define COUTn 256

// Exact f32 squared distance, no FMA contraction: matches ((dx*dx+dy*dy)+dz*dz)
static __device__ __forceinline__ float sqdist(float ax, float ay, float az,
                                               float bx, float by, float bz) {
    float dx = __fsub_rn(ax, bx);
    float dy = __fsub_rn(ay, by);
    float dz = __fsub_rn(az, bz);
    return __fadd_rn(__fadd_rn(__fmul_rn(dx, dx), __fmul_rn(dy, dy)), __fmul_rn(dz, dz));
}

static __device__ __forceinline__ unsigned long long u64max(unsigned long long a,
                                                            unsigned long long b) {
    return a > b ? a : b;
}

// xor-swizzle a u64 across lanes within 32-lane groups (BitMode ds_swizzle)
#define SWZ_U64(key, OFF)                                                        \
    do {                                                                         \
        unsigned _lo = (unsigned)__builtin_amdgcn_ds_swizzle((int)(key), OFF);   \
        unsigned _hi = (unsigned)__builtin_amdgcn_ds_swizzle((int)((key) >> 32), OFF); \
        unsigned long long _o = ((unsigned long long)_hi << 32) | _lo;           \
        if (_o > (key)) (key) = _o;                                              \
    } while (0)

// ---------------- Kernel: farthest point sampling ---------------------------
// Exact argmax/tie-break semantics (validated via output 0 in r6-r9).
// Reduction: per-step each thread writes its u64 key (double-buffered, ONE
// barrier); each lane reads 8 key-PAIRS with pattern (lane&31)+32j so each
// 32-lane half covers all 512 keys; 4-level register tree; then a 5-level
// xor butterfly entirely via ds_swizzle (no bpermute, no xor-32 level).
__global__ __launch_bounds__(512) void k_fps(const float* __restrict__ xyz,
                                             float* __restrict__ out_xyz) {
    __shared__ __align__(16) float xs[Nn], ys[Nn], zs[Nn];
    __shared__ __align__(16) unsigned long long kbuf[2][512];
    const int b = blockIdx.x;
    const int tid = threadIdx.x;
    const int lane = tid & 63;
    const float* base = xyz + (size_t)b * 3 * Nn;
    for (int i = tid; i < Nn; i += 512) {
        xs[i] = base[i];
        ys[i] = base[Nn + i];
        zs[i] = base[2 * Nn + i];
    }
    __syncthreads();
    float px[8], py[8], pz[8], dist[8];
#pragma unroll
    for (int j = 0; j < 8; ++j) {
        int p = tid + j * 512;
        px[j] = xs[p]; py[j] = ys[p]; pz[j] = zs[p];
        dist[j] = 3.402823466e+38f;   // FLT_MAX, matches jnp.finfo(f32).max
    }
    int last = 0;
    if (tid == 0) {
        out_xyz[(size_t)(b * Sn) * 3 + 0] = xs[0];
        out_xyz[(size_t)(b * Sn) * 3 + 1] = ys[0];
        out_xyz[(size_t)(b * Sn) * 3 + 2] = zs[0];
    }
    for (int s = 1; s < Sn; ++s) {
        const float cx = xs[last], cy = ys[last], cz = zs[last];
        float mv = -1.0f; int mi = 0;
#pragma unroll
        for (int j = 0; j < 8; ++j) {
            float d = sqdist(px[j], py[j], pz[j], cx, cy, cz);
            float nd = fminf(dist[j], d);
            dist[j] = nd;
            if (nd > mv) { mv = nd; mi = tid + j * 512; }  // strict >: first-max wins
        }
        // pack: dist bits high (dist>=0 so f32 bit order == value order),
        // (N-1-idx) low so u64-max tie-breaks to the SMALLEST index.
        kbuf[s & 1][tid] =
            ((unsigned long long)__float_as_uint(mv) << 32) | (unsigned)(Nn - 1 - mi);
        __syncthreads();
        // stage 1: 8 b128 pair-reads; pairs (lane&31)+32j cover all 512 keys
        // within each 32-lane half (both halves do identical redundant work).
        const ulonglong2* kb = (const ulonglong2*)kbuf[s & 1];
        const int l5 = lane & 31;
        ulonglong2 v0 = kb[l5];
        ulonglong2 v1 = kb[l5 + 32];
        ulonglong2 v2 = kb[l5 + 64];
        ulonglong2 v3 = kb[l5 + 96];
        ulonglong2 v4 = kb[l5 + 128];
        ulonglong2 v5 = kb[l5 + 160];
        ulonglong2 v6 = kb[l5 + 192];
        ulonglong2 v7 = kb[l5 + 224];
        unsigned long long a0 = u64max(v0.x, v0.y), a1 = u64max(v1.x, v1.y);
        unsigned long long a2 = u64max(v2.x, v2.y), a3 = u64max(v3.x, v3.y);
        unsigned long long a4 = u64max(v4.x, v4.y), a5 = u64max(v5.x, v5.y);
        unsigned long long a6 = u64max(v6.x, v6.y), a7 = u64max(v7.x, v7.y);
        unsigned long long key = u64max(u64max(u64max(a0, a1), u64max(a2, a3)),
                                        u64max(u64max(a4, a5), u64max(a6, a7)));
        // stage 2: xor butterfly within 32-lane groups, pure ds_swizzle
        SWZ_U64(key, 0x041F);   // xor 1
        SWZ_U64(key, 0x081F);   // xor 2
        SWZ_U64(key, 0x101F);   // xor 4
        SWZ_U64(key, 0x201F);   // xor 8
        SWZ_U64(key, 0x401F);   // xor 16
        const int nl = Nn - 1 - (int)(unsigned)(key & 0xFFFFFFFFull);
        if (tid == 0) {
            out_xyz[(size_t)(b * Sn + s) * 3 + 0] = xs[nl];
            out_xyz[(size_t)(b * Sn + s) * 3 + 1] = ys[nl];
            out_xyz[(size_t)(b * Sn + s) * 3 + 2] = zs[nl];
        }
        last = nl;
        // no second barrier: next step uses the other kbuf half; re-writes of
        // this half occur only after the s+1 barrier (program order per wave).
    }
}

// ---- Ball query: one WAVE per center, ballot + rank-scatter ----------------
// Semantics identical to the validated sequential scan: first K in-ball
// indices in ascending order, padded with the first. No register arrays with
// dynamic indices (each in-ball lane writes its own rank slot directly).
__global__ __launch_bounds__(256) void k_ball(const float* __restrict__ xyz,
                                              const float* __restrict__ out_xyz,
                                              int* __restrict__ ball_idx) {
    __shared__ __align__(16) float xs[Nn], ys[Nn], zs[Nn];
    const int b = blockIdx.x >> 4;          // 16 blocks per batch
    const int blk = blockIdx.x & 15;
    const int tid = threadIdx.x;
    const int wave = tid >> 6, lane = tid & 63;
    const float* base = xyz + (size_t)b * 3 * Nn;
    for (int i = tid; i < Nn; i += 256) {
        xs[i] = base[i]; ys[i] = base[Nn + i]; zs[i] = base[2 * Nn + i];
    }
    __syncthreads();
    for (int ci = 0; ci < 16; ++ci) {
        const int c = blk * 64 + ci * 4 + wave;        // 0..1023
        const size_t cg = (size_t)b * Sn + c;
        const float cx = out_xyz[cg * 3 + 0];
        const float cy = out_xyz[cg * 3 + 1];
        const float cz = out_xyz[cg * 3 + 2];
        int cnt = 0;
        int idx0 = -1;
        for (int chunk = 0; chunk < Nn / 64; ++chunk) {
            const int p = chunk * 64 + lane;
            const float d2 = sqdist(xs[p], ys[p], zs[p], cx, cy, cz);
            const bool in = (d2 <= 0.04f);             // f32(0.2*0.2)
            const unsigned long long m = __ballot(in);
            if (m != 0ull) {
                if (idx0 < 0) idx0 = chunk * 64 + __builtin_ctzll(m);
                const int rank = cnt + __popcll(m & ((1ull << lane) - 1ull));
                if (in && rank < Kn)
                    ball_idx[cg * Kn + rank] = p;       // ascending by construction
                cnt += __popcll(m);
                if (cnt >= Kn) break;                   // wave-uniform
            }
        }
        if (lane < Kn && lane >= cnt)                   // pad with first index
            ball_idx[cg * Kn + lane] = idx0;
    }
}

// ---- Feature kernel: one WAVE per center, each lane owns 4 out-channels ----
// Unchanged from validated r9 version.
__global__ __launch_bounds__(256) void k_feat(const float* __restrict__ feat,
                                              const float* __restrict__ conv_w,
                                              const float* __restrict__ conv_b,
                                              const float* __restrict__ bn_g,
                                              const float* __restrict__ bn_b,
                                              const float* __restrict__ bn_m,
                                              const float* __restrict__ bn_v,
                                              const int* __restrict__ ball_idx,
                                              float* __restrict__ out_feat) {
    const int wave = threadIdx.x >> 6, lane = threadIdx.x & 63;
    const int bs = blockIdx.x * 4 + wave;     // 0 .. B*S-1
    const int b  = bs >> 10;                  // Sn = 1024
    const float* fb = feat + (size_t)b * CINn * Nn;
    const float4* cw4 = (const float4*)conv_w;   // [o][f/4]

    int pt[Kn];
#pragma unroll
    for (int k = 0; k < Kn; ++k) pt[k] = ball_idx[(size_t)bs * Kn + k];

    float acc[4][Kn];
#pragma unroll
    for (int j = 0; j < 4; ++j)
#pragma unroll
        for (int k = 0; k < Kn; ++k) acc[j][k] = 0.0f;

    for (int f4 = 0; f4 < CINn / 4; ++f4) {
        float4 w[4];
#pragma unroll
        for (int j = 0; j < 4; ++j)
            w[j] = cw4[(size_t)(lane + 64 * j) * (CINn / 4) + f4];
#pragma unroll
        for (int c = 0; c < 4; ++c) {
            const float* frc = fb + (size_t)(f4 * 4 + c) * Nn;
            float fv[Kn];
#pragma unroll
            for (int k = 0; k < Kn; ++k) fv[k] = frc[pt[k]];
#pragma unroll
            for (int j = 0; j < 4; ++j) {
                const float wc = ((const float*)&w[j])[c];
#pragma unroll
                for (int k = 0; k < Kn; ++k) acc[j][k] += fv[k] * wc;
            }
        }
    }

    // epilogue: identical math/order to the validated kernel
#pragma unroll
    for (int j = 0; j < 4; ++j) {
        const int o = lane + 64 * j;
        const float bias = conv_b[o];
        const float g = bn_g[o], be = bn_b[o], mn = bn_m[o], vr = bn_v[o];
        const float inv = sqrtf(vr + 1e-5f);
        float mx = -3.402823466e+38f;
#pragma unroll
        for (int k = 0; k < Kn; ++k) {
            float z = acc[j][k] + bias;
            float y = g * (z - mn) / inv + be;
            y = fmaxf(y, 0.0f);              // ReLU before max, literal order
            mx = fmaxf(mx, y);
        }
        out_feat[(size_t)bs * COUTn + o] = mx;
    }
}

extern "C" void kernel_launch(void* const* d_in, const int* in_sizes, int n_in,
                              void* d_out, int out_size, void* d_ws, size_t ws_size,
                              hipStream_t stream) {
    const float* xyz    = (const float*)d_in[0];
    const float* feat   = (const float*)d_in[1];
    const float* conv_w = (const float*)d_in[2];
    const float* conv_b = (const float*)d_in[3];
    const float* bn_g   = (const float*)d_in[4];
    const float* bn_b   = (const float*)d_in[5];
    const float* bn_m   = (const float*)d_in[6];
    const float* bn_v   = (const float*)d_in[7];

    float* out_xyz  = (float*)d_out;
    float* out_feat = out_xyz + (size_t)Bn * Sn * 3;

    int* ball_idx = (int*)d_ws;   // 512 KB

    k_fps <<<dim3(Bn),            dim3(512), 0, stream>>>(xyz, out_xyz);
    k_ball<<<dim3(Bn * 16),       dim3(256), 0, stream>>>(xyz, out_xyz, ball_idx);
    k_feat<<<dim3(Bn * Sn / 4),   dim3(256), 0, stream>>>(feat, conv_w, conv_b,
                                                          bn_g, bn_b, bn_m, bn_v,
                                                          ball_idx, out_feat);
}

// Round 11
// 1272.254 us; speedup vs baseline: 2.4743x; 1.0129x over previous
//
#include <hip/hip_runtime.h>
#include <hip/hip_bf16.h>
#include <stdint.h>

#define Bn   16
#define Nn   4096
#define Sn   1024
#define Kn   8
#define CINn 128
#define COUTn 256

// Exact f32 squared distance, no FMA contraction: matches ((dx*dx+dy*dy)+dz*dz)
static __device__ __forceinline__ float sqdist(float ax, float ay, float az,
                                               float bx, float by, float bz) {
    float dx = __fsub_rn(ax, bx);
    float dy = __fsub_rn(ay, by);
    float dz = __fsub_rn(az, bz);
    return __fadd_rn(__fadd_rn(__fmul_rn(dx, dx), __fmul_rn(dy, dy)), __fmul_rn(dz, dz));
}

static __device__ __forceinline__ unsigned long long u64max(unsigned long long a,
                                                            unsigned long long b) {
    return a > b ? a : b;
}

// xor-swizzle a u64 across lanes within 32-lane groups (BitMode ds_swizzle)
#define SWZ_U64(key, OFF)                                                        \
    do {                                                                         \
        unsigned _lo = (unsigned)__builtin_amdgcn_ds_swizzle((int)(key), OFF);   \
        unsigned _hi = (unsigned)__builtin_amdgcn_ds_swizzle((int)((key) >> 32), OFF); \
        unsigned long long _o = ((unsigned long long)_hi << 32) | _lo;           \
        if (_o > (key)) (key) = _o;                                              \
    } while (0)

// ---------------- Kernel: farthest point sampling (UNCHANGED, validated) ----
__global__ __launch_bounds__(512) void k_fps(const float* __restrict__ xyz,
                                             float* __restrict__ out_xyz) {
    __shared__ __align__(16) float xs[Nn], ys[Nn], zs[Nn];
    __shared__ __align__(16) unsigned long long kbuf[2][512];
    const int b = blockIdx.x;
    const int tid = threadIdx.x;
    const int lane = tid & 63;
    const float* base = xyz + (size_t)b * 3 * Nn;
    for (int i = tid; i < Nn; i += 512) {
        xs[i] = base[i];
        ys[i] = base[Nn + i];
        zs[i] = base[2 * Nn + i];
    }
    __syncthreads();
    float px[8], py[8], pz[8], dist[8];
#pragma unroll
    for (int j = 0; j < 8; ++j) {
        int p = tid + j * 512;
        px[j] = xs[p]; py[j] = ys[p]; pz[j] = zs[p];
        dist[j] = 3.402823466e+38f;   // FLT_MAX, matches jnp.finfo(f32).max
    }
    int last = 0;
    if (tid == 0) {
        out_xyz[(size_t)(b * Sn) * 3 + 0] = xs[0];
        out_xyz[(size_t)(b * Sn) * 3 + 1] = ys[0];
        out_xyz[(size_t)(b * Sn) * 3 + 2] = zs[0];
    }
    for (int s = 1; s < Sn; ++s) {
        const float cx = xs[last], cy = ys[last], cz = zs[last];
        float mv = -1.0f; int mi = 0;
#pragma unroll
        for (int j = 0; j < 8; ++j) {
            float d = sqdist(px[j], py[j], pz[j], cx, cy, cz);
            float nd = fminf(dist[j], d);
            dist[j] = nd;
            if (nd > mv) { mv = nd; mi = tid + j * 512; }  // strict >: first-max wins
        }
        kbuf[s & 1][tid] =
            ((unsigned long long)__float_as_uint(mv) << 32) | (unsigned)(Nn - 1 - mi);
        __syncthreads();
        const ulonglong2* kb = (const ulonglong2*)kbuf[s & 1];
        const int l5 = lane & 31;
        ulonglong2 v0 = kb[l5];
        ulonglong2 v1 = kb[l5 + 32];
        ulonglong2 v2 = kb[l5 + 64];
        ulonglong2 v3 = kb[l5 + 96];
        ulonglong2 v4 = kb[l5 + 128];
        ulonglong2 v5 = kb[l5 + 160];
        ulonglong2 v6 = kb[l5 + 192];
        ulonglong2 v7 = kb[l5 + 224];
        unsigned long long a0 = u64max(v0.x, v0.y), a1 = u64max(v1.x, v1.y);
        unsigned long long a2 = u64max(v2.x, v2.y), a3 = u64max(v3.x, v3.y);
        unsigned long long a4 = u64max(v4.x, v4.y), a5 = u64max(v5.x, v5.y);
        unsigned long long a6 = u64max(v6.x, v6.y), a7 = u64max(v7.x, v7.y);
        unsigned long long key = u64max(u64max(u64max(a0, a1), u64max(a2, a3)),
                                        u64max(u64max(a4, a5), u64max(a6, a7)));
        SWZ_U64(key, 0x041F);   // xor 1
        SWZ_U64(key, 0x081F);   // xor 2
        SWZ_U64(key, 0x101F);   // xor 4
        SWZ_U64(key, 0x201F);   // xor 8
        SWZ_U64(key, 0x401F);   // xor 16
        const int nl = Nn - 1 - (int)(unsigned)(key & 0xFFFFFFFFull);
        if (tid == 0) {
            out_xyz[(size_t)(b * Sn + s) * 3 + 0] = xs[nl];
            out_xyz[(size_t)(b * Sn + s) * 3 + 1] = ys[nl];
            out_xyz[(size_t)(b * Sn + s) * 3 + 2] = zs[nl];
        }
        last = nl;
    }
}

// ---- Ball query (UNCHANGED, validated): wave per center, ballot+rank-scatter
__global__ __launch_bounds__(256) void k_ball(const float* __restrict__ xyz,
                                              const float* __restrict__ out_xyz,
                                              int* __restrict__ ball_idx) {
    __shared__ __align__(16) float xs[Nn], ys[Nn], zs[Nn];
    const int b = blockIdx.x >> 4;          // 16 blocks per batch
    const int blk = blockIdx.x & 15;
    const int tid = threadIdx.x;
    const int wave = tid >> 6, lane = tid & 63;
    const float* base = xyz + (size_t)b * 3 * Nn;
    for (int i = tid; i < Nn; i += 256) {
        xs[i] = base[i]; ys[i] = base[Nn + i]; zs[i] = base[2 * Nn + i];
    }
    __syncthreads();
    for (int ci = 0; ci < 16; ++ci) {
        const int c = blk * 64 + ci * 4 + wave;        // 0..1023
        const size_t cg = (size_t)b * Sn + c;
        const float cx = out_xyz[cg * 3 + 0];
        const float cy = out_xyz[cg * 3 + 1];
        const float cz = out_xyz[cg * 3 + 2];
        int cnt = 0;
        int idx0 = -1;
        for (int chunk = 0; chunk < Nn / 64; ++chunk) {
            const int p = chunk * 64 + lane;
            const float d2 = sqdist(xs[p], ys[p], zs[p], cx, cy, cz);
            const bool in = (d2 <= 0.04f);             // f32(0.2*0.2)
            const unsigned long long m = __ballot(in);
            if (m != 0ull) {
                if (idx0 < 0) idx0 = chunk * 64 + __builtin_ctzll(m);
                const int rank = cnt + __popcll(m & ((1ull << lane) - 1ull));
                if (in && rank < Kn)
                    ball_idx[cg * Kn + rank] = p;       // ascending by construction
                cnt += __popcll(m);
                if (cnt >= Kn) break;                   // wave-uniform
            }
        }
        if (lane < Kn && lane >= cnt)                   // pad with first index
            ball_idx[cg * Kn + lane] = idx0;
    }
}

// ---- Transpose: feat [B][CIN][N] -> featT [B][N][CIN], LDS 64x64 tiles -----
__global__ __launch_bounds__(256) void k_tr(const float* __restrict__ feat,
                                            float* __restrict__ featT) {
    __shared__ float t[64][65];
    const int b  = blockIdx.x >> 7;          // 16 batches
    const int ft = (blockIdx.x >> 6) & 1;    // 2 f-tiles
    const int nt = blockIdx.x & 63;          // 64 n-tiles
    const int col = threadIdx.x & 63;
    const int r0  = threadIdx.x >> 6;        // 0..3
    const float* src = feat + (size_t)b * CINn * Nn;
    float* dst = featT + (size_t)b * Nn * CINn;
#pragma unroll
    for (int i = 0; i < 16; ++i) {
        const int row = r0 + i * 4;          // f_local
        t[row][col] = src[(size_t)(ft * 64 + row) * Nn + nt * 64 + col];
    }
    __syncthreads();
#pragma unroll
    for (int i = 0; i < 16; ++i) {
        const int row = r0 + i * 4;          // n_local
        dst[(size_t)(nt * 64 + row) * CINn + ft * 64 + col] = t[col][row];
    }
}

// ---- Feature kernel (featT path): one WAVE per center, coalesced gather ----
// Same accumulation order per accumulator as the validated r9/r10 kernel.
// Blocks XCD-grouped: all 256 blocks of a batch land on one XCD (g%8 mapping)
// so featT's 2MB/batch working set stays in that XCD's 4MB L2.
__global__ __launch_bounds__(256) void k_feat(const float* __restrict__ featT,
                                              const float* __restrict__ conv_w,
                                              const float* __restrict__ conv_b,
                                              const float* __restrict__ bn_g,
                                              const float* __restrict__ bn_b,
                                              const float* __restrict__ bn_m,
                                              const float* __restrict__ bn_v,
                                              const int* __restrict__ ball_idx,
                                              float* __restrict__ out_feat) {
    const int wave = threadIdx.x >> 6, lane = threadIdx.x & 63;
    const int g = blockIdx.x;                 // 0..4095
    const int xcd = g & 7, r = g >> 3;        // batch = xcd*2 + (r&1)
    const int b = xcd * 2 + (r & 1);
    const int bs = b * Sn + (r >> 1) * 4 + wave;
    const float4* ft4 = (const float4*)(featT + (size_t)b * Nn * CINn);
    const float4* cw4 = (const float4*)conv_w;   // [o][f/4]

    int pt[Kn];
#pragma unroll
    for (int k = 0; k < Kn; ++k) pt[k] = ball_idx[(size_t)bs * Kn + k];

    float acc[4][Kn];
#pragma unroll
    for (int j = 0; j < 4; ++j)
#pragma unroll
        for (int k = 0; k < Kn; ++k) acc[j][k] = 0.0f;

    for (int f4 = 0; f4 < CINn / 4; ++f4) {
        float4 w[4];
#pragma unroll
        for (int j = 0; j < 4; ++j)
            w[j] = cw4[(size_t)(lane + 64 * j) * (CINn / 4) + f4];
        float4 fv[Kn];
#pragma unroll
        for (int k = 0; k < Kn; ++k)
            fv[k] = ft4[(size_t)pt[k] * (CINn / 4) + f4];   // wave-uniform, 16B
#pragma unroll
        for (int c = 0; c < 4; ++c) {
#pragma unroll
            for (int j = 0; j < 4; ++j) {
                const float wc = ((const float*)&w[j])[c];
#pragma unroll
                for (int k = 0; k < Kn; ++k)
                    acc[j][k] += ((const float*)&fv[k])[c] * wc;
            }
        }
    }

#pragma unroll
    for (int j = 0; j < 4; ++j) {
        const int o = lane + 64 * j;
        const float bias = conv_b[o];
        const float gg = bn_g[o], be = bn_b[o], mn = bn_m[o], vr = bn_v[o];
        const float inv = sqrtf(vr + 1e-5f);
        float mx = -3.402823466e+38f;
#pragma unroll
        for (int k = 0; k < Kn; ++k) {
            float z = acc[j][k] + bias;
            float y = gg * (z - mn) / inv + be;
            y = fmaxf(y, 0.0f);              // ReLU before max, literal order
            mx = fmaxf(mx, y);
        }
        out_feat[(size_t)bs * COUTn + o] = mx;
    }
}

// ---- Fallback feature kernel (validated r10 text): direct strided gather ---
__global__ __launch_bounds__(256) void k_feat_direct(const float* __restrict__ feat,
                                              const float* __restrict__ conv_w,
                                              const float* __restrict__ conv_b,
                                              const float* __restrict__ bn_g,
                                              const float* __restrict__ bn_b,
                                              const float* __restrict__ bn_m,
                                              const float* __restrict__ bn_v,
                                              const int* __restrict__ ball_idx,
                                              float* __restrict__ out_feat) {
    const int wave = threadIdx.x >> 6, lane = threadIdx.x & 63;
    const int bs = blockIdx.x * 4 + wave;
    const int b  = bs >> 10;
    const float* fb = feat + (size_t)b * CINn * Nn;
    const float4* cw4 = (const float4*)conv_w;

    int pt[Kn];
#pragma unroll
    for (int k = 0; k < Kn; ++k) pt[k] = ball_idx[(size_t)bs * Kn + k];

    float acc[4][Kn];
#pragma unroll
    for (int j = 0; j < 4; ++j)
#pragma unroll
        for (int k = 0; k < Kn; ++k) acc[j][k] = 0.0f;

    for (int f4 = 0; f4 < CINn / 4; ++f4) {
        float4 w[4];
#pragma unroll
        for (int j = 0; j < 4; ++j)
            w[j] = cw4[(size_t)(lane + 64 * j) * (CINn / 4) + f4];
#pragma unroll
        for (int c = 0; c < 4; ++c) {
            const float* frc = fb + (size_t)(f4 * 4 + c) * Nn;
            float fv[Kn];
#pragma unroll
            for (int k = 0; k < Kn; ++k) fv[k] = frc[pt[k]];
#pragma unroll
            for (int j = 0; j < 4; ++j) {
                const float wc = ((const float*)&w[j])[c];
#pragma unroll
                for (int k = 0; k < Kn; ++k) acc[j][k] += fv[k] * wc;
            }
        }
    }

#pragma unroll
    for (int j = 0; j < 4; ++j) {
        const int o = lane + 64 * j;
        const float bias = conv_b[o];
        const float g = bn_g[o], be = bn_b[o], mn = bn_m[o], vr = bn_v[o];
        const float inv = sqrtf(vr + 1e-5f);
        float mx = -3.402823466e+38f;
#pragma unroll
        for (int k = 0; k < Kn; ++k) {
            float z = acc[j][k] + bias;
            float y = g * (z - mn) / inv + be;
            y = fmaxf(y, 0.0f);
            mx = fmaxf(mx, y);
        }
        out_feat[(size_t)bs * COUTn + o] = mx;
    }
}

extern "C" void kernel_launch(void* const* d_in, const int* in_sizes, int n_in,
                              void* d_out, int out_size, void* d_ws, size_t ws_size,
                              hipStream_t stream) {
    const float* xyz    = (const float*)d_in[0];
    const float* feat   = (const float*)d_in[1];
    const float* conv_w = (const float*)d_in[2];
    const float* conv_b = (const float*)d_in[3];
    const float* bn_g   = (const float*)d_in[4];
    const float* bn_b   = (const float*)d_in[5];
    const float* bn_m   = (const float*)d_in[6];
    const float* bn_v   = (const float*)d_in[7];

    float* out_xyz  = (float*)d_out;
    float* out_feat = out_xyz + (size_t)Bn * Sn * 3;

    char* ws = (char*)d_ws;
    int*   ball_idx = (int*)ws;                       // 512 KB
    float* featT    = (float*)(ws + 524288);          // 32 MB
    const bool haveT = ws_size >= (size_t)524288 + (size_t)Bn * Nn * CINn * 4;

    k_fps <<<dim3(Bn),      dim3(512), 0, stream>>>(xyz, out_xyz);
    k_ball<<<dim3(Bn * 16), dim3(256), 0, stream>>>(xyz, out_xyz, ball_idx);
    if (haveT) {
        k_tr  <<<dim3(Bn * 128),    dim3(256), 0, stream>>>(feat, featT);
        k_feat<<<dim3(Bn * Sn / 4), dim3(256), 0, stream>>>(featT, conv_w, conv_b,
                                                            bn_g, bn_b, bn_m, bn_v,
                                                            ball_idx, out_feat);
    } else {
        k_feat_direct<<<dim3(Bn * Sn / 4), dim3(256), 0, stream>>>(feat, conv_w, conv_b,
                                                            bn_g, bn_b, bn_m, bn_v,
                                                            ball_idx, out_feat);
    }
}